// Round 1
// baseline (255.192 us; speedup 1.0000x reference)
//
#include <hip/hip_runtime.h>

#define BB 16
#define NN 2000
#define HH 720
#define WW 1280
#define NPT (BB*NN)          // 32000 keypoints total
#define PBLOCKS (NPT/4)      // 8000 blocks, 4 waves (points) each
#define CHUNK (NN/8)         // 250 m-entries per scanning thread
#define KNN_BX ((NN+31)/32)  // 63 blocks per batch

// ---------------- bilinear sample, exact reference semantics ----------------
__device__ __forceinline__ float bilin(const float* __restrict__ im, float px, float py) {
    px = fminf(fmaxf(px, 0.f), (float)(WW - 1));
    py = fminf(fmaxf(py, 0.f), (float)(HH - 1));
    float x0f = floorf(px), y0f = floorf(py);
    float fx = px - x0f, fy = py - y0f;
    int x0 = min(max((int)x0f, 0), WW - 1);
    int x1 = min(x0 + 1, WW - 1);
    int y0 = min(max((int)y0f, 0), HH - 1);
    int y1 = min(y0 + 1, HH - 1);
    const float* r0 = im + (size_t)y0 * WW;
    const float* r1 = im + (size_t)y1 * WW;
    float v00 = r0[x0], v01 = r0[x1], v10 = r1[x0], v11 = r1[x1];
    return (v00 * (1.f - fx) + v01 * fx) * (1.f - fy)
         + (v10 * (1.f - fx) + v11 * fx) * fy;
}

// ---------------- Kernel A: per-point patch loss + projection ----------------
// one wave per keypoint; lanes 0..48 = one patch sample pair each
__global__ __launch_bounds__(256) void point_kernel(
    const float* __restrict__ lg, const float* __restrict__ rg,
    const float* __restrict__ kpl, const float* __restrict__ kpr,
    const float* __restrict__ scores, const float* __restrict__ Q,
    float4* __restrict__ pts, float* __restrict__ partials)
{
    __shared__ float part[8];
    if (threadIdx.x < 8) part[threadIdx.x] = 0.f;
    __syncthreads();

    int wv = threadIdx.x >> 6, lane = threadIdx.x & 63;
    int pt = blockIdx.x * 4 + wv;              // grid is exactly NPT/4
    int b = pt / NN;

    float kxl = kpl[pt * 2 + 0], kyl = kpl[pt * 2 + 1];
    float kxr = kpr[pt * 2 + 0], kyr = kpr[pt * 2 + 1];
    float sc  = scores[pt];

    float vl = 0.f, vr = 0.f, adiff = 0.f;
    if (lane < 49) {
        float ox = (float)(lane % 7 - 3);
        float oy = (float)(lane / 7 - 3);
        const float* iml = lg + (size_t)b * HH * WW;
        const float* imr = rg + (size_t)b * HH * WW;
        vl = bilin(iml, kxl + ox, kyl + oy);
        vr = bilin(imr, kxr + ox, kyr + oy);
        adiff = fabsf(vl - vr);
    }
    float cl = __shfl(vl, 24, 64);   // center sample (3,3) -> ravel idx 24
    float cr = __shfl(vr, 24, 64);
    #pragma unroll
    for (int off = 32; off > 0; off >>= 1) adiff += __shfl_down(adiff, off, 64);

    if (lane == 0) {
        float diff = adiff / 49.f;
        float isb  = (cl > 0.02f) ? 1.f : 0.f;     // BRIGHT
        float w    = sc * isb;
        float ydiff = fabsf(kyl - kyr);
        float dc = fabsf(cl - cr);
        float sl1 = (dc < 1.f) ? 0.5f * dc * dc : dc - 0.5f;

        const float* q = Q + b * 16;
        float dsp = kxl - kxr;
        float p0 = q[0]*kxl + q[1]*kyl + q[2]*dsp  + q[3];
        float p1 = q[4]*kxl + q[5]*kyl + q[6]*dsp  + q[7];
        float p2 = q[8]*kxl + q[9]*kyl + q[10]*dsp + q[11];
        float p3 = q[12]*kxl + q[13]*kyl + q[14]*dsp + q[15];
        float Wc = fmaxf(p3, 1e-6f);
        float X = p0 / Wc, Y = p1 / Wc, Z = p2 / Wc;
        bool valid = (Z > 100.f) && (Z < 30000.f) && (sc > 0.1f);
        float x  = X / 1000.f;
        float hh = Y / 1000.f;
        float y  = Z / 1000.f;
        float sq = x * x + y * y;
        if (!valid) { x = 0.f; y = 0.f; sq = 1e18f; }  // sentinel: huge d2, keeps true h
        pts[pt] = make_float4(x, y, sq, hh);

        atomicAdd(&part[0], sc);
        atomicAdd(&part[1], ydiff * sc);
        atomicAdd(&part[2], ydiff);
        atomicAdd(&part[3], w);
        atomicAdd(&part[4], diff * w);
        atomicAdd(&part[5], sl1 * w);
        atomicAdd(&part[6], (sc > 0.1f) ? 1.f : 0.f);
    }
    __syncthreads();
    if (threadIdx.x < 8) partials[blockIdx.x * 8 + threadIdx.x] = part[threadIdx.x];
}

// ---------------- Kernel B: KNN (top-5 excl self) + smooth/slope/zmean ------
// block = 256 threads = 32 points x 8 chunks; whole batch resident in LDS
__global__ __launch_bounds__(256) void knn_kernel(
    const float4* __restrict__ pts, float* __restrict__ batch_acc)
{
    __shared__ float4 tile[NN];       // 32000 B
    __shared__ float  mD[256 * 5];    //  5120 B
    __shared__ int    mI[256 * 5];    //  5120 B

    int b = blockIdx.y;
    for (int i = threadIdx.x; i < NN; i += 256) tile[i] = pts[b * NN + i];
    __syncthreads();

    int chunk = threadIdx.x >> 5;     // 0..7
    int pidx  = threadIdx.x & 31;     // 0..31
    int n = blockIdx.x * 32 + pidx;

    float D0=1e29f, D1=1e29f, D2=1e29f, D3=1e29f, D4=1e29f;
    int   I0=0, I1=0, I2=0, I3=0, I4=0;
    bool act = false;
    float xn = 0.f, yn = 0.f, sqn = 0.f, hn = 0.f;
    if (n < NN) {
        float4 me = tile[n];
        xn = me.x; yn = me.y; sqn = me.z; hn = me.w;
        act = (sqn < 1e17f);          // valid flag via sentinel
    }

    if (act) {
        int m0 = chunk * CHUNK;
        for (int mm = 0; mm < CHUNK; ++mm) {
            int m = m0 + mm;
            float4 o = tile[m];
            float dot = xn * o.x + yn * o.y;
            float d2 = sqn + o.z - 2.f * dot;
            d2 = (m == n) ? 1e30f : fmaxf(d2, 1e-12f);  // exclude self; clamp like ref
            // branchless sorted insert, strict < keeps jax stable-tie order
            bool c0 = d2 < D0, c1 = d2 < D1, c2 = d2 < D2, c3 = d2 < D3, c4 = d2 < D4;
            D4 = c3 ? D3 : (c4 ? d2 : D4);  I4 = c3 ? I3 : (c4 ? m : I4);
            D3 = c2 ? D2 : (c3 ? d2 : D3);  I3 = c2 ? I2 : (c3 ? m : I3);
            D2 = c1 ? D1 : (c2 ? d2 : D2);  I2 = c1 ? I1 : (c2 ? m : I2);
            D1 = c0 ? D0 : (c1 ? d2 : D1);  I1 = c0 ? I0 : (c1 ? m : I1);
            D0 = c0 ? d2 : D0;              I0 = c0 ? m : I0;
        }
    }
    int base = threadIdx.x * 5;
    mD[base+0]=D0; mD[base+1]=D1; mD[base+2]=D2; mD[base+3]=D3; mD[base+4]=D4;
    mI[base+0]=I0; mI[base+1]=I1; mI[base+2]=I2; mI[base+3]=I3; mI[base+4]=I4;
    __syncthreads();

    float ls = 0.f, pen = 0.f, hacc = 0.f, cnt = 0.f;
    if (threadIdx.x < 32 && n < NN && act) {
        float E0=1e31f, E1=1e31f, E2=1e31f, E3=1e31f, E4=1e31f;
        int   J0=0, J1=0, J2=0, J3=0, J4=0;
        // merge 8 chunk-lists in ascending-m order (stable ties preserved)
        #pragma unroll
        for (int c = 0; c < 8; ++c) {
            int tb = (c * 32 + pidx) * 5;
            #pragma unroll
            for (int j = 0; j < 5; ++j) {
                float d2 = mD[tb + j]; int m = mI[tb + j];
                bool c0 = d2 < E0, c1 = d2 < E1, c2 = d2 < E2, c3 = d2 < E3, c4 = d2 < E4;
                E4 = c3 ? E3 : (c4 ? d2 : E4);  J4 = c3 ? J3 : (c4 ? m : J4);
                E3 = c2 ? E2 : (c3 ? d2 : E3);  J3 = c2 ? J2 : (c3 ? m : J3);
                E2 = c1 ? E1 : (c2 ? d2 : E2);  J2 = c1 ? J1 : (c2 ? m : J2);
                E1 = c0 ? E0 : (c1 ? d2 : E1);  J1 = c0 ? J0 : (c1 ? m : J1);
                E0 = c0 ? d2 : E0;              J0 = c0 ? m : J0;
            }
        }
        float h0 = tile[J0].w, h1 = tile[J1].w, h2 = tile[J2].w, h3 = tile[J3].w, h4 = tile[J4].w;
        float lm = (h0 + h1 + h2 + h3 + h4) / 5.f;
        float dd = fabsf(hn - lm);
        ls = (dd < 0.01f) ? 0.5f * dd * dd / 0.01f : dd - 0.005f;  // smooth_l1 beta=0.01
        float nd, sl;
        nd = fmaxf(sqrtf(E0), 0.001f); sl = fabsf(h0 - hn) / nd; pen += fmaxf(sl - 0.4f, 0.f);
        nd = fmaxf(sqrtf(E1), 0.001f); sl = fabsf(h1 - hn) / nd; pen += fmaxf(sl - 0.4f, 0.f);
        nd = fmaxf(sqrtf(E2), 0.001f); sl = fabsf(h2 - hn) / nd; pen += fmaxf(sl - 0.4f, 0.f);
        nd = fmaxf(sqrtf(E3), 0.001f); sl = fabsf(h3 - hn) / nd; pen += fmaxf(sl - 0.4f, 0.f);
        nd = fmaxf(sqrtf(E4), 0.001f); sl = fabsf(h4 - hn) / nd; pen += fmaxf(sl - 0.4f, 0.f);
        hacc = hn;
        cnt  = 1.f;
    }
    if (threadIdx.x < 32) {   // threads 0..31 = wave 0 lanes 0..31
        #pragma unroll
        for (int off = 16; off > 0; off >>= 1) {
            ls   += __shfl_down(ls,   off, 32);
            pen  += __shfl_down(pen,  off, 32);
            hacc += __shfl_down(hacc, off, 32);
            cnt  += __shfl_down(cnt,  off, 32);
        }
        if (threadIdx.x == 0) {
            atomicAdd(&batch_acc[b * 4 + 0], cnt);
            atomicAdd(&batch_acc[b * 4 + 1], ls);
            atomicAdd(&batch_acc[b * 4 + 2], pen);
            atomicAdd(&batch_acc[b * 4 + 3], hacc);
        }
    }
}

// ---------------- Kernel C: final scalar epilogue ----------------
__global__ __launch_bounds__(256) void final_kernel(
    const float* __restrict__ partials, const float* __restrict__ batch_acc,
    float* __restrict__ out)
{
    float s[8] = {0,0,0,0,0,0,0,0};
    for (int r = threadIdx.x; r < PBLOCKS; r += 256) {
        #pragma unroll
        for (int k = 0; k < 8; ++k) s[k] += partials[r * 8 + k];
    }
    #pragma unroll
    for (int off = 32; off > 0; off >>= 1) {
        #pragma unroll
        for (int k = 0; k < 8; ++k) s[k] += __shfl_down(s[k], off, 64);
    }
    __shared__ float wsum_s[4][8];
    int wv = threadIdx.x >> 6, lane = threadIdx.x & 63;
    if (lane == 0) {
        #pragma unroll
        for (int k = 0; k < 8; ++k) wsum_s[wv][k] = s[k];
    }
    __syncthreads();
    if (threadIdx.x == 0) {
        float t[8];
        #pragma unroll
        for (int k = 0; k < 8; ++k)
            t[k] = wsum_s[0][k] + wsum_s[1][k] + wsum_s[2][k] + wsum_s[3][k];
        float ssc = t[0], yds = t[1], yd = t[2], wsum = t[3], dw = t[4], iw = t[5], cnts = t[6];

        float l_epi = (ssc > 1e-4f) ? yds / fmaxf(ssc, 1e-12f) : yd / (float)NPT;
        float safe = fmaxf(wsum, 1e-12f);
        float l_photo = (wsum > 1e-4f) ? (dw / safe + iw / safe) : 0.f;

        float als = 0.f, alsl = 0.f, alz = 0.f, okc = 0.f;
        for (int b = 0; b < BB; ++b) {
            float nvf  = batch_acc[b * 4 + 0];
            float lsb  = batch_acc[b * 4 + 1];
            float penb = batch_acc[b * 4 + 2];
            float hb   = batch_acc[b * 4 + 3];
            float nv = fmaxf(nvf, 1.f);
            float ok = (nvf >= 10.f) ? 1.f : 0.f;
            als  += ok * (lsb / nv);
            alsl += ok * (penb / (nv * 5.f));   // K = 5
            alz  += ok * fabsf(hb / nv);
            okc  += ok;
        }
        float nb = fmaxf(okc, 1.f);
        bool gate = (cnts >= 10.f) && (okc > 0.f);
        out[0] = l_photo;
        out[1] = l_epi;
        out[2] = gate ? als / nb : 0.f;
        out[3] = gate ? alsl / nb : 0.f;
        out[4] = gate ? alz / nb : 0.f;
    }
}

extern "C" void kernel_launch(void* const* d_in, const int* in_sizes, int n_in,
                              void* d_out, int out_size, void* d_ws, size_t ws_size,
                              hipStream_t stream)
{
    const float* lg     = (const float*)d_in[0];
    const float* rg     = (const float*)d_in[1];
    const float* kpl    = (const float*)d_in[2];
    const float* kpr    = (const float*)d_in[3];
    const float* scores = (const float*)d_in[4];
    const float* Q      = (const float*)d_in[5];
    float* out = (float*)d_out;

    char* ws = (char*)d_ws;
    float4* pts      = (float4*)ws;                 // 512000 B
    float*  partials = (float*)(ws + 512000);       // 8000*8*4 = 256000 B
    float*  batch_acc= (float*)(ws + 768000);       // 16*4*4 = 256 B

    hipMemsetAsync(batch_acc, 0, BB * 4 * sizeof(float), stream);
    point_kernel<<<PBLOCKS, 256, 0, stream>>>(lg, rg, kpl, kpr, scores, Q, pts, partials);
    knn_kernel<<<dim3(KNN_BX, BB), 256, 0, stream>>>(pts, batch_acc);
    final_kernel<<<1, 256, 0, stream>>>(partials, batch_acc, out);
}